// Round 2
// baseline (69.971 us; speedup 1.0000x reference)
//
#include <hip/hip_runtime.h>

typedef unsigned long long u64;

#define NB 64      // batch of graphs
#define NN 128     // nodes per graph
#define NITER 5
#define NGEN 6     // initial labels + 5 WL iterations
#define TT (NB*NN) // 8192 total nodes

__device__ __forceinline__ u64 mix64(u64 x) {
    u64 z = x + 0x9E3779B97F4A7C15ULL;
    z = (z ^ (z >> 30)) * 0xBF58476D1CE4E5B9ULL;
    z = (z ^ (z >> 27)) * 0x94D049BB133111EBULL;
    return z ^ (z >> 31);
}

// One block per graph (64 blocks x 128 threads). Thread i owns node i.
// Packs adjacency row into a 128-bit mask once, then runs 5 WL iterations
// entirely in LDS. Writes all 6 label generations to hgen[gen][b][i].
__global__ __launch_bounds__(128) void wl_propagate(const float* __restrict__ adj,
                                                    const int* __restrict__ labels,
                                                    u64* __restrict__ hgen) {
    const int b = blockIdx.x;
    const int i = threadIdx.x;
    __shared__ u64 h_sh[NN];
    __shared__ u64 g_sh[NN];

    // adjacency bitmask for my row (adj entries are exactly 0.0 or 1.0)
    const float* arow = adj + (size_t)b * NN * NN + (size_t)i * NN;
    u64 bits0 = 0, bits1 = 0;
    #pragma unroll
    for (int j = 0; j < 64; ++j) {
        if (arow[j]      > 0.5f) bits0 |= (1ULL << j);
        if (arow[64 + j] > 0.5f) bits1 |= (1ULL << j);
    }

    u64 h = mix64((u64)(unsigned)labels[b * NN + i]);
    h_sh[i] = h;
    hgen[0 * TT + b * NN + i] = h;
    __syncthreads();

    for (int it = 0; it < NITER; ++it) {
        g_sh[i] = mix64(h_sh[i] ^ 0xD1B54A32D192ED03ULL);
        __syncthreads();
        u64 nsum = 0;
        #pragma unroll
        for (int j = 0; j < 64; ++j) {
            if ((bits0 >> j) & 1ULL) nsum += g_sh[j];
            if ((bits1 >> j) & 1ULL) nsum += g_sh[64 + j];
        }
        u64 hn = mix64(mix64(h_sh[i]) + nsum);
        __syncthreads();
        h_sh[i] = hn;
        hgen[(it + 1) * TT + b * NN + i] = hn;
        __syncthreads();
    }
}

// One block per (b1,b2) pair: count label equalities over all 6 generations.
// 256 threads: thread t handles row i = t>>1, half-row j0 = (t&1)*64.
__global__ __launch_bounds__(256) void wl_count(const u64* __restrict__ hgen,
                                                float* __restrict__ Kraw) {
    const int pair = blockIdx.x;
    const int b1 = pair >> 6;
    const int b2 = pair & 63;
    const int t = threadIdx.x;
    __shared__ u64 Ash[NN];
    __shared__ u64 Bsh[NN];

    unsigned cnt = 0;
    for (int gen = 0; gen < NGEN; ++gen) {
        if (t < NN) Ash[t]      = hgen[gen * TT + b1 * NN + t];
        else        Bsh[t - NN] = hgen[gen * TT + b2 * NN + (t - NN)];
        __syncthreads();
        const u64 a = Ash[t >> 1];
        const int j0 = (t & 1) << 6;
        #pragma unroll
        for (int j = 0; j < 64; ++j) {
            cnt += (a == Bsh[j0 + j]) ? 1u : 0u;
        }
        __syncthreads();
    }

    // reduce 256 threads -> 1
    #pragma unroll
    for (int off = 32; off > 0; off >>= 1) cnt += __shfl_down(cnt, off);
    __shared__ unsigned part[4];
    const int wid = t >> 6;
    if ((t & 63) == 0) part[wid] = cnt;
    __syncthreads();
    if (t == 0) Kraw[pair] = (float)(part[0] + part[1] + part[2] + part[3]);
}

// Cosine-normalize: out[b1,b2] = K / sqrt(K[b1,b1]*K[b2,b2])
__global__ __launch_bounds__(256) void wl_norm(const float* __restrict__ Kraw,
                                               float* __restrict__ out) {
    const int idx = blockIdx.x * 256 + threadIdx.x;
    if (idx >= NB * NB) return;
    const int b1 = idx >> 6;
    const int b2 = idx & 63;
    const float d1 = Kraw[b1 * NB + b1];
    const float d2 = Kraw[b2 * NB + b2];
    out[idx] = Kraw[idx] / (sqrtf(d1) * sqrtf(d2));
}

extern "C" void kernel_launch(void* const* d_in, const int* in_sizes, int n_in,
                              void* d_out, int out_size, void* d_ws, size_t ws_size,
                              hipStream_t stream) {
    const float* adj   = (const float*)d_in[0];   // [64,128,128] fp32 (0/1)
    const int*  labels = (const int*)d_in[1];     // [64,128] int32
    float* out = (float*)d_out;                   // [64,64] fp32

    u64*   hgen = (u64*)d_ws;                                   // 6*8192*8 = 384 KiB
    float* Kraw = (float*)((char*)d_ws + (size_t)NGEN * TT * 8); // 16 KiB

    wl_propagate<<<NB, NN, 0, stream>>>(adj, labels, hgen);
    wl_count<<<NB * NB, 256, 0, stream>>>(hgen, Kraw);
    wl_norm<<<(NB * NB + 255) / 256, 256, 0, stream>>>(Kraw, out);
}

// Round 3
// 35.628 us; speedup vs baseline: 1.9639x; 1.9639x over previous
//
#include <hip/hip_runtime.h>

typedef unsigned long long u64;

#define NB 64      // batch of graphs
#define NN 128     // nodes per graph
#define NITER 5
#define NGEN 6     // initial labels + 5 WL iterations
#define TT (NB*NN) // 8192 total nodes
#define NPAIR (NB*(NB+1)/2)  // 2080 triangular pairs
#define SALT 0xD1B54A32D192ED03ULL

__device__ __forceinline__ u64 mix64(u64 x) {
    u64 z = x + 0x9E3779B97F4A7C15ULL;
    z = (z ^ (z >> 30)) * 0xBF58476D1CE4E5B9ULL;
    z = (z ^ (z >> 27)) * 0x94D049BB133111EBULL;
    return z ^ (z >> 31);
}

// One block per graph, 256 threads (4 waves).
// Phase 1: pack adjacency into 128-bit row masks via coalesced loads + ballot.
// Phase 2: 5 WL iterations in LDS; neighbor sums via sparse ctz iteration,
//          2 threads per node (one per 64-bit mask half).
__global__ __launch_bounds__(256) void wl_propagate(const float* __restrict__ adj,
                                                    const int* __restrict__ labels,
                                                    u64* __restrict__ hgen) {
    const int b = blockIdx.x;
    const int t = threadIdx.x;
    const int wave = t >> 6;   // 0..3
    const int lane = t & 63;

    __shared__ u64 bits_sh[NN][2];
    __shared__ u64 h_sh[NN];
    __shared__ u64 g_sh[NN];
    __shared__ u64 psum[2][NN];

    // ---- pack adjacency: wave w handles rows w*32 .. w*32+31, coalesced ----
    const float* abase = adj + (size_t)b * NN * NN;
    #pragma unroll 4
    for (int k = 0; k < 32; ++k) {
        const int row = wave * 32 + k;
        const float* arow = abase + (size_t)row * NN;
        u64 m0 = __ballot(arow[lane] > 0.5f);
        u64 m1 = __ballot(arow[64 + lane] > 0.5f);
        if (lane == 0) { bits_sh[row][0] = m0; bits_sh[row][1] = m1; }
    }

    if (t < NN) {
        u64 h = mix64((u64)(unsigned)labels[b * NN + t]);
        h_sh[t] = h;
        hgen[b * NN + t] = h;  // generation 0
    }
    __syncthreads();

    for (int it = 0; it < NITER; ++it) {
        if (t < NN) g_sh[t] = mix64(h_sh[t] ^ SALT);
        __syncthreads();
        {
            const int i = t & 127;
            const int half = t >> 7;
            u64 m = bits_sh[i][half];
            const u64* gp = g_sh + (half << 6);
            u64 s = 0;
            while (m) {
                int j = __builtin_ctzll(m);
                m &= m - 1;
                s += gp[j];
            }
            psum[half][i] = s;
        }
        __syncthreads();
        if (t < NN) {
            u64 hn = mix64(mix64(h_sh[t]) + psum[0][t] + psum[1][t]);
            h_sh[t] = hn;
            hgen[(size_t)(it + 1) * TT + b * NN + t] = hn;
        }
        __syncthreads();
    }
}

// One block per unordered pair (b1>=b2): count label equalities over 6 gens.
// 256 threads: thread t = (ag<<3)|bg owns A rows ag*4..+3 (in registers) and
// B cols bg*16..+15. B is streamed as u64 pairs (ds_read_b128) with a
// per-group rotation (jj+bg)&7 so the 8 distinct addresses per wave step
// cover all 32 LDS banks (conflict-free).
__global__ __launch_bounds__(256) void wl_count(const u64* __restrict__ hgen,
                                                float* __restrict__ Kraw) {
    const int p = blockIdx.x;
    // decode triangular index p -> (b1, b2), b2 <= b1
    int r = (int)((sqrtf(8.0f * (float)p + 1.0f) - 1.0f) * 0.5f);
    while ((r + 1) * (r + 2) / 2 <= p) ++r;
    while (r * (r + 1) / 2 > p) --r;
    const int b1 = r;
    const int b2 = p - r * (r + 1) / 2;

    const int t = threadIdx.x;
    const int ag = t >> 3;   // 0..31
    const int bg = t & 7;    // 0..7

    __shared__ u64 Ash[NN];
    __shared__ u64 Bsh[NN];

    unsigned cnt = 0;
    for (int gen = 0; gen < NGEN; ++gen) {
        if (t < NN) Ash[t]      = hgen[(size_t)gen * TT + b1 * NN + t];
        else        Bsh[t - NN] = hgen[(size_t)gen * TT + b2 * NN + (t - NN)];
        __syncthreads();

        const u64 a0 = Ash[ag * 4 + 0];
        const u64 a1 = Ash[ag * 4 + 1];
        const u64 a2 = Ash[ag * 4 + 2];
        const u64 a3 = Ash[ag * 4 + 3];
        const u64* Bp = Bsh + bg * 16;
        #pragma unroll
        for (int jj = 0; jj < 8; ++jj) {
            const int idx = ((jj + bg) & 7) * 2;
            const u64 v0 = Bp[idx];
            const u64 v1 = Bp[idx + 1];
            cnt += (a0 == v0); cnt += (a0 == v1);
            cnt += (a1 == v0); cnt += (a1 == v1);
            cnt += (a2 == v0); cnt += (a2 == v1);
            cnt += (a3 == v0); cnt += (a3 == v1);
        }
        __syncthreads();
    }

    // reduce 256 threads -> 1
    #pragma unroll
    for (int off = 32; off > 0; off >>= 1) cnt += __shfl_down(cnt, off);
    __shared__ unsigned part[4];
    if ((t & 63) == 0) part[t >> 6] = cnt;
    __syncthreads();
    if (t == 0) {
        const float v = (float)(part[0] + part[1] + part[2] + part[3]);
        Kraw[b1 * NB + b2] = v;
        Kraw[b2 * NB + b1] = v;
    }
}

// Cosine-normalize: out[b1,b2] = K / sqrt(K[b1,b1]*K[b2,b2])
__global__ __launch_bounds__(256) void wl_norm(const float* __restrict__ Kraw,
                                               float* __restrict__ out) {
    const int idx = blockIdx.x * 256 + threadIdx.x;
    if (idx >= NB * NB) return;
    const int b1 = idx >> 6;
    const int b2 = idx & 63;
    const float d1 = Kraw[b1 * NB + b1];
    const float d2 = Kraw[b2 * NB + b2];
    out[idx] = Kraw[idx] / (sqrtf(d1) * sqrtf(d2));
}

extern "C" void kernel_launch(void* const* d_in, const int* in_sizes, int n_in,
                              void* d_out, int out_size, void* d_ws, size_t ws_size,
                              hipStream_t stream) {
    const float* adj   = (const float*)d_in[0];   // [64,128,128] fp32 (0/1)
    const int*  labels = (const int*)d_in[1];     // [64,128] int32
    float* out = (float*)d_out;                   // [64,64] fp32

    u64*   hgen = (u64*)d_ws;                                    // 6*8192*8 = 384 KiB
    float* Kraw = (float*)((char*)d_ws + (size_t)NGEN * TT * 8); // 16 KiB

    wl_propagate<<<NB, 256, 0, stream>>>(adj, labels, hgen);
    wl_count<<<NPAIR, 256, 0, stream>>>(hgen, Kraw);
    wl_norm<<<(NB * NB + 255) / 256, 256, 0, stream>>>(Kraw, out);
}

// Round 4
// 31.936 us; speedup vs baseline: 2.1910x; 1.1156x over previous
//
#include <hip/hip_runtime.h>

typedef unsigned long long u64;
typedef unsigned int u32;

#define NB 64      // batch of graphs
#define NN 128     // nodes per graph
#define NITER 5
#define NGEN 6     // initial labels + 5 WL iterations
#define SALT 0xD1B54A32D192ED03ULL
#define NPAIR_OFF (NB*(NB-1)/2)  // 2016 strict lower-triangular pairs

__device__ __forceinline__ u64 mix64(u64 x) {
    u64 z = x + 0x9E3779B97F4A7C15ULL;
    z = (z ^ (z >> 30)) * 0xBF58476D1CE4E5B9ULL;
    z = (z ^ (z >> 27)) * 0x94D049BB133111EBULL;
    return z ^ (z >> 31);
}

// One block per graph, 512 threads (8 waves).
// 1) pack adjacency into 128-bit row masks (coalesced loads + ballot)
// 2) 5 WL iterations in LDS (4 threads per node for neighbor sums)
// 3) self-pair count -> Kdiag[b], out[b][b] = 1.0
// Label layout written to global: hgen[b][gen][node] (6 KB contiguous/graph).
__global__ __launch_bounds__(512) void wl_propagate(const float* __restrict__ adj,
                                                    const int* __restrict__ labels,
                                                    u64* __restrict__ hgen,
                                                    float* __restrict__ Kdiag,
                                                    float* __restrict__ out) {
    const int b = blockIdx.x;
    const int t = threadIdx.x;
    const int wave = t >> 6;   // 0..7
    const int lane = t & 63;

    __shared__ u64 bits_sh[NN][2];
    __shared__ u64 h_sh[NN];
    __shared__ u64 g_sh[NN];
    __shared__ u64 hall[NGEN][NN];
    __shared__ u64 psum[4][NN];
    __shared__ u32 part[8];

    // ---- pack adjacency: wave w handles rows w*16 .. w*16+15 ----
    const float* abase = adj + (size_t)b * NN * NN;
    #pragma unroll 4
    for (int k = 0; k < 16; ++k) {
        const int row = wave * 16 + k;
        const float* arow = abase + (size_t)row * NN;
        u64 m0 = __ballot(arow[lane] > 0.5f);
        u64 m1 = __ballot(arow[64 + lane] > 0.5f);
        if (lane == 0) { bits_sh[row][0] = m0; bits_sh[row][1] = m1; }
    }

    if (t < NN) {
        u64 h = mix64((u64)(unsigned)labels[b * NN + t]);
        h_sh[t] = h;
        hall[0][t] = h;
        hgen[(size_t)b * (NGEN * NN) + t] = h;
    }
    __syncthreads();

    for (int it = 0; it < NITER; ++it) {
        if (t < NN) g_sh[t] = mix64(h_sh[t] ^ SALT);
        __syncthreads();
        {   // 4 threads per node, each owns a 32-bit quarter of the mask
            const int i = t & 127;
            const int q = t >> 7;  // 0..3
            u32 m = (u32)(bits_sh[i][q >> 1] >> ((q & 1) * 32));
            const u64* gp = g_sh + q * 32;
            u64 s = 0;
            while (m) {
                int j = __builtin_ctz(m);
                m &= m - 1;
                s += gp[j];
            }
            psum[q][i] = s;
        }
        __syncthreads();
        if (t < NN) {
            u64 hn = mix64(mix64(h_sh[t]) + psum[0][t] + psum[1][t] + psum[2][t] + psum[3][t]);
            h_sh[t] = hn;
            hall[it + 1][t] = hn;
            hgen[(size_t)b * (NGEN * NN) + (it + 1) * NN + t] = hn;
        }
        __syncthreads();
    }

    // ---- diagonal self-count: thread owns node i = t&127, j-quarter jq = t>>7 ----
    {
        const int i = t & 127;
        const int jq = t >> 7;
        u32 cnt = 0;
        for (int g = 0; g < NGEN; ++g) {
            const u64 a = hall[g][i];
            const u64* jp = &hall[g][jq * 32];   // wave-uniform base -> broadcast reads
            #pragma unroll
            for (int jj = 0; jj < 32; ++jj) cnt += (a == jp[jj]) ? 1u : 0u;
        }
        #pragma unroll
        for (int off = 32; off > 0; off >>= 1) cnt += __shfl_down(cnt, off);
        if (lane == 0) part[wave] = cnt;
        __syncthreads();
        if (t == 0) {
            u32 d = 0;
            #pragma unroll
            for (int w = 0; w < 8; ++w) d += part[w];
            Kdiag[b] = (float)d;
            out[b * NB + b] = 1.0f;
        }
    }
}

// One block per strict lower pair (b1>b2). Stage all 6 generations of both
// graphs (12 KB LDS) with coalesced b128 loads -> ONE barrier, then a pure
// register compare loop: thread t=(ag<<3)|bg holds A rows ag*4..+3 in VGPRs,
// streams B via rotated ds_read_b128 (rotation (jj+bg)&7 spreads the 8
// distinct wave addresses over all 32 banks). Writes normalized output.
__global__ __launch_bounds__(256) void wl_count(const u64* __restrict__ hgen,
                                                const float* __restrict__ Kdiag,
                                                float* __restrict__ out) {
    const int p = blockIdx.x;
    // decode p -> (b1,b2), p = b1*(b1-1)/2 + b2, 0 <= b2 < b1
    int b1 = (int)((1.0f + sqrtf(1.0f + 8.0f * (float)p)) * 0.5f);
    while (b1 * (b1 - 1) / 2 > p) --b1;
    while ((b1 + 1) * b1 / 2 <= p) ++b1;
    const int b2 = p - b1 * (b1 - 1) / 2;

    const int t = threadIdx.x;
    const int ag = t >> 3;   // 0..31
    const int bg = t & 7;    // 0..7

    __shared__ u64 Ash[NGEN][NN];
    __shared__ u64 Bsh[NGEN][NN];

    // stage both graphs' 6 generations: 768 x 16B chunks over 256 threads
    {
        const ulonglong2* sA = (const ulonglong2*)(hgen + (size_t)b1 * (NGEN * NN));
        const ulonglong2* sB = (const ulonglong2*)(hgen + (size_t)b2 * (NGEN * NN));
        ulonglong2* dA = (ulonglong2*)&Ash[0][0];
        ulonglong2* dB = (ulonglong2*)&Bsh[0][0];
        #pragma unroll
        for (int k = 0; k < 3; ++k) {
            const int idx = t + 256 * k;     // 0..767; wave-uniform A/B split
            if (idx < 384) dA[idx] = sA[idx];
            else           dB[idx - 384] = sB[idx - 384];
        }
    }
    __syncthreads();

    u32 cnt = 0;
    for (int g = 0; g < NGEN; ++g) {
        const u64 a0 = Ash[g][ag * 4 + 0];
        const u64 a1 = Ash[g][ag * 4 + 1];
        const u64 a2 = Ash[g][ag * 4 + 2];
        const u64 a3 = Ash[g][ag * 4 + 3];
        const u64* Bp = &Bsh[g][bg * 16];
        #pragma unroll
        for (int jj = 0; jj < 8; ++jj) {
            const int idx = ((jj + bg) & 7) * 2;
            const u64 v0 = Bp[idx];
            const u64 v1 = Bp[idx + 1];
            cnt += (a0 == v0); cnt += (a0 == v1);
            cnt += (a1 == v0); cnt += (a1 == v1);
            cnt += (a2 == v0); cnt += (a2 == v1);
            cnt += (a3 == v0); cnt += (a3 == v1);
        }
    }

    #pragma unroll
    for (int off = 32; off > 0; off >>= 1) cnt += __shfl_down(cnt, off);
    __shared__ u32 part[4];
    if ((t & 63) == 0) part[t >> 6] = cnt;
    __syncthreads();
    if (t == 0) {
        const float v = (float)(part[0] + part[1] + part[2] + part[3])
                      / (sqrtf(Kdiag[b1]) * sqrtf(Kdiag[b2]));
        out[b1 * NB + b2] = v;
        out[b2 * NB + b1] = v;
    }
}

extern "C" void kernel_launch(void* const* d_in, const int* in_sizes, int n_in,
                              void* d_out, int out_size, void* d_ws, size_t ws_size,
                              hipStream_t stream) {
    const float* adj   = (const float*)d_in[0];   // [64,128,128] fp32 (0/1)
    const int*  labels = (const int*)d_in[1];     // [64,128] int32
    float* out = (float*)d_out;                   // [64,64] fp32

    u64*   hgen  = (u64*)d_ws;                                        // 64*6*128*8 = 384 KiB
    float* Kdiag = (float*)((char*)d_ws + (size_t)NB * NGEN * NN * 8); // 256 B

    wl_propagate<<<NB, 512, 0, stream>>>(adj, labels, hgen, Kdiag, out);
    wl_count<<<NPAIR_OFF, 256, 0, stream>>>(hgen, Kdiag, out);
}